// Round 5
// baseline (205.611 us; speedup 1.0000x reference)
//
#include <hip/hip_runtime.h>
#include <cstdint>

typedef __attribute__((ext_vector_type(8))) __bf16 bf16x8;
typedef __attribute__((ext_vector_type(4))) float f32x4;
typedef __attribute__((ext_vector_type(8))) short short8;
typedef __attribute__((ext_vector_type(4))) float float4v;
typedef __attribute__((ext_vector_type(4))) unsigned uint4v;
typedef __attribute__((ext_vector_type(4))) unsigned short ushort4v;

__device__ __forceinline__ unsigned short f2bf(float f) {
    unsigned u = __builtin_bit_cast(unsigned, f);
    u += 0x7fffu + ((u >> 16) & 1u);   // RNE
    return (unsigned short)(u >> 16);
}
__device__ __forceinline__ float bf2f(unsigned short s) {
    return __builtin_bit_cast(float, (unsigned)s << 16);
}
__device__ __forceinline__ f32x4 mfma_bf16(bf16x8 a, bf16x8 b, f32x4 c) {
    return __builtin_amdgcn_mfma_f32_16x16x32_bf16(a, b, c, 0, 0, 0);
}
// pack 2 f32 -> 2 bf16 in one u32 (lo = first arg)
__device__ __forceinline__ unsigned pkbf(float lo, float hi) {
    unsigned r;
    asm("v_cvt_pk_bf16_f32 %0, %1, %2" : "=v"(r) : "v"(lo), "v"(hi));
    return r;
}

#define GLD16(g, l)                                                                     \
    __builtin_amdgcn_global_load_lds((const __attribute__((address_space(1))) void*)(g), \
                                     (__attribute__((address_space(3))) void*)(l), 16, 0, 0)

// ---------------------------------------------------------------------------
// fp32 -> bf16 conversion, 8 elems/thread.
// ---------------------------------------------------------------------------
__global__ void __launch_bounds__(256) cvt_f32_bf16(const float* __restrict__ src,
                                                    unsigned short* __restrict__ dst, int n8) {
    const int stride = gridDim.x * blockDim.x;
    for (int i = blockIdx.x * blockDim.x + threadIdx.x; i < n8; i += stride) {
        const float4v* s = (const float4v*)(src + (size_t)i * 8);
        float4v v0 = s[0], v1 = s[1];
        short8 o;
        o[0] = (short)f2bf(v0[0]); o[1] = (short)f2bf(v0[1]);
        o[2] = (short)f2bf(v0[2]); o[3] = (short)f2bf(v0[3]);
        o[4] = (short)f2bf(v1[0]); o[5] = (short)f2bf(v1[1]);
        o[6] = (short)f2bf(v1[2]); o[7] = (short)f2bf(v1[3]);
        *(short8*)(dst + (size_t)i * 8) = o;
    }
}

// ---------------------------------------------------------------------------
// C[M,N] = A[M,K]*B[N,K]^T + bias[N].  128x128 tile, BK=32, 4 waves, m97 structure.
// MODE 0: f32 C (ldc=N).   MODE 1 (QKV): n0<2048 -> bf16 qk buffer (ldc=2048);
//   n0>=2048 -> V part written TRANSPOSED into vT[bh][d=64][token=2048] bf16.
// ---------------------------------------------------------------------------
template <int MODE>
__global__ void __launch_bounds__(256) gemm_bt(const unsigned short* __restrict__ A,
                                               const unsigned short* __restrict__ B,
                                               const float* __restrict__ bias,
                                               void* __restrict__ C,
                                               unsigned short* __restrict__ vT,
                                               int M, int N, int K) {
    __shared__ __attribute__((aligned(16))) unsigned short As[128 * 32];
    __shared__ __attribute__((aligned(16))) unsigned short Bs[128 * 32];
    const int tid = threadIdx.x;
    const int w = tid >> 6, lane = tid & 63;
    const int a = lane & 15, g = lane >> 4;
    const int m0 = blockIdx.y * 128, n0 = blockIdx.x * 128;
    const int wr = (w >> 1) * 64, wc = (w & 1) * 64;

    f32x4 acc[4][4];
#pragma unroll
    for (int i = 0; i < 4; i++)
#pragma unroll
        for (int j = 0; j < 4; j++) acc[i][j] = (f32x4)(0.0f);

    const int r0 = tid >> 2;
    const int c0 = (tid & 3) * 8;
    const unsigned short* gA0 = A + (size_t)(m0 + r0) * K + c0;
    const unsigned short* gA1 = A + (size_t)(m0 + 64 + r0) * K + c0;
    const unsigned short* gB0 = B + (size_t)(n0 + r0) * K + c0;
    const unsigned short* gB1 = B + (size_t)(n0 + 64 + r0) * K + c0;
    char* ldsA = (char*)As + w * 1024;
    char* ldsB = (char*)Bs + w * 1024;

    for (int k0 = 0; k0 < K; k0 += 32) {
        GLD16(gA0 + k0, ldsA);
        GLD16(gA1 + k0, ldsA + 4096);
        GLD16(gB0 + k0, ldsB);
        GLD16(gB1 + k0, ldsB + 4096);
        __syncthreads();

        bf16x8 af[4], bfr[4];
#pragma unroll
        for (int i = 0; i < 4; i++) {
            af[i]  = *(const bf16x8*)&As[(wr + i * 16 + a) * 32 + g * 8];
            bfr[i] = *(const bf16x8*)&Bs[(wc + i * 16 + a) * 32 + g * 8];
        }
#pragma unroll
        for (int i = 0; i < 4; i++)
#pragma unroll
            for (int j = 0; j < 4; j++) acc[i][j] = mfma_bf16(af[i], bfr[j], acc[i][j]);
        __syncthreads();
    }

#pragma unroll
    for (int j = 0; j < 4; j++) {
        const int col = n0 + wc + j * 16 + a;
        const float bv = bias[col];
        if (MODE == 0) {
            float* Cf = (float*)C;
#pragma unroll
            for (int i = 0; i < 4; i++)
#pragma unroll
                for (int jr = 0; jr < 4; jr++) {
                    const int row = m0 + wr + i * 16 + g * 4 + jr;
                    Cf[(size_t)row * N + col] = acc[i][j][jr] + bv;
                }
        } else if (n0 < 2048) {  // Q/K part -> bf16, ldc = 2048
            unsigned short* Cb = (unsigned short*)C;
#pragma unroll
            for (int i = 0; i < 4; i++)
#pragma unroll
                for (int jr = 0; jr < 4; jr++) {
                    const int row = m0 + wr + i * 16 + g * 4 + jr;
                    Cb[(size_t)row * 2048 + col] = f2bf(acc[i][j][jr] + bv);
                }
        } else {  // V part -> vT[(b*16+h)][d][token], 4-token packs
            const int vd = col - 2048;
            const int hh = vd >> 6, dd = vd & 63;
#pragma unroll
            for (int i = 0; i < 4; i++) {
                const int token0 = m0 + wr + i * 16 + g * 4;
                const int bb = token0 >> 11, kl = token0 & 2047;
                ushort4v st;
#pragma unroll
                for (int jr = 0; jr < 4; jr++) st[jr] = f2bf(acc[i][j][jr] + bv);
                *(ushort4v*)(vT + ((size_t)((bb << 4) + hh) * 64 + dd) * 2048 + kl) = st;
            }
        }
    }
}

// ===========================================================================
// Causal flash attention v5: swapped QK^T, in-register softmax (exp2 domain),
// in-block K-SPLIT (flash-decoding combine via LDS), heavy-first dispatch,
// K and V register prefetch one tile ahead, per-lane l, defer-max.
// qk: [B*S, 2048] bf16 (Q | K), vT: [32][64][2048] bf16.
// Block = 256 thr = 4 waves: wave w -> q-subgroup (w&1), k-half (w>>1).
// q-tile = 32 rows.  Grid = 2048 blocks (32 bh x 64 q-tiles).
// ===========================================================================

#define QKT(p, qf)                                                      \
    {                                                                   \
        _Pragma("unroll") for (int nf_ = 0; nf_ < 4; nf_++) {           \
            f32x4 acc_ = (f32x4)(0.0f);                                 \
            acc_ = mfma_bf16(ka[nf_], qf[0], acc_);                     \
            acc_ = mfma_bf16(kc[nf_], qf[1], acc_);                     \
            p[nf_] = acc_;                                              \
        }                                                               \
    }

#define DIAG_MASK(p, qs_, k0_)                                          \
    {                                                                   \
        _Pragma("unroll") for (int nf_ = 0; nf_ < 4; nf_++) {           \
            const int kb_ = (k0_) + ((nf_ & 2) << 4) + ((nf_ & 1) << 2) + 8 * g; \
            _Pragma("unroll") for (int e_ = 0; e_ < 4; e_++)            \
                if (kb_ + e_ > (qs_)) p[nf_][e_] = -1e30f;              \
        }                                                               \
    }

// p in log2 domain. Updates m_,l_,of_; produces packed bf16 B-fragments.
#define SOFTMAX_PACK(p, m_, l_, of_, pf0, pf1)                          \
    {                                                                   \
        float x0 = fmaxf(fmaxf(p[0][0], p[0][1]), fmaxf(p[0][2], p[0][3])); \
        float x1 = fmaxf(fmaxf(p[1][0], p[1][1]), fmaxf(p[1][2], p[1][3])); \
        float x2 = fmaxf(fmaxf(p[2][0], p[2][1]), fmaxf(p[2][2], p[2][3])); \
        float x3 = fmaxf(fmaxf(p[3][0], p[3][1]), fmaxf(p[3][2], p[3][3])); \
        float mx = fmaxf(fmaxf(x0, x1), fmaxf(x2, x3));                 \
        mx = fmaxf(mx, __shfl_xor(mx, 16));                             \
        mx = fmaxf(mx, __shfl_xor(mx, 32));                             \
        if (!__all(mx <= m_ + 8.0f)) {                                  \
            const float mn_ = fmaxf(m_, mx);                            \
            const float al_ = __builtin_amdgcn_exp2f(m_ - mn_);         \
            l_ *= al_;                                                  \
            _Pragma("unroll") for (int d_ = 0; d_ < 4; d_++) of_[d_] = of_[d_] * al_; \
            m_ = mn_;                                                   \
        }                                                               \
        float rs_ = 0.0f;                                               \
        _Pragma("unroll") for (int nf_ = 0; nf_ < 4; nf_++)             \
            _Pragma("unroll") for (int e_ = 0; e_ < 4; e_++) {          \
                p[nf_][e_] = __builtin_amdgcn_exp2f(p[nf_][e_] - m_);   \
                rs_ += p[nf_][e_];                                      \
            }                                                           \
        l_ += rs_;                                                      \
        uint4v u0_, u1_;                                                \
        u0_[0] = pkbf(p[0][0], p[0][1]); u0_[1] = pkbf(p[0][2], p[0][3]); \
        u0_[2] = pkbf(p[1][0], p[1][1]); u0_[3] = pkbf(p[1][2], p[1][3]); \
        u1_[0] = pkbf(p[2][0], p[2][1]); u1_[1] = pkbf(p[2][2], p[2][3]); \
        u1_[2] = pkbf(p[3][0], p[3][1]); u1_[3] = pkbf(p[3][2], p[3][3]); \
        pf0 = __builtin_bit_cast(bf16x8, u0_);                          \
        pf1 = __builtin_bit_cast(bf16x8, u1_);                          \
    }

#define PV(of_, pf0, pf1)                                               \
    {                                                                   \
        _Pragma("unroll") for (int df_ = 0; df_ < 4; df_++) {           \
            of_[df_] = mfma_bf16(va[df_], pf0, of_[df_]);               \
            of_[df_] = mfma_bf16(vc[df_], pf1, of_[df_]);               \
        }                                                               \
    }

#define PREFETCH_K()                                                    \
    {                                                                   \
        _Pragma("unroll") for (int nf_ = 0; nf_ < 4; nf_++) {           \
            ka[nf_] = *(const bf16x8*)kp[nf_];                          \
            kc[nf_] = *(const bf16x8*)(kp[nf_] + 32);                   \
            kp[nf_] += 64 * 2048;                                       \
        }                                                               \
    }

#define PREFETCH_V()                                                    \
    {                                                                   \
        _Pragma("unroll") for (int df_ = 0; df_ < 4; df_++) {           \
            va[df_] = *(const bf16x8*)vp[df_];                          \
            vc[df_] = *(const bf16x8*)(vp[df_] + 32);                   \
            vp[df_] += 64;                                              \
        }                                                               \
    }

__global__ void __launch_bounds__(256, 4) attn_fwd(const unsigned short* __restrict__ qk,
                                                   const unsigned short* __restrict__ vT,
                                                   unsigned short* __restrict__ o) {
    constexpr int SL = 2048, DH = 64, LDQ = 2048;
    constexpr float GAMMA = 0.18033688011112042f;  // 0.125 * log2(e)
    const int flat = blockIdx.x;                   // 2048 blocks
    const int bh = flat & 31;                      // bh%8 -> XCD pinning
    const int qt = 63 - (flat >> 5);               // 32-row q-tile, heavy first
    const int b = bh >> 4, h = bh & 15;
    const int tid = threadIdx.x;
    const int w = tid >> 6, lane = tid & 63;
    const int n = lane & 15, g = lane >> 4;
    const int sgrp = w & 1;                        // q-subgroup (16 rows)
    const int khalf = w >> 1;                      // k-range half

    const int q0 = qt * 32;
    const int qs = q0 + sgrp * 16 + n;             // this lane's q row
    const int nt = (qt >> 1) + 1;                  // total 64-wide k-tiles
    const int hsp = (nt + 1) >> 1;                 // split point
    const int ts = khalf ? hsp : 0;
    const int te = khalf ? nt : hsp;

    // merge buffer: [sgrp][lane][of 16 | m | l]
    __shared__ float mrg[2][64][18];

    // Q fragments (B-operand), prescaled into log2 domain
    bf16x8 qf[2];
    {
        const unsigned short* qp = qk + (size_t)(b * SL + qs) * LDQ + h * DH + g * 8;
        short8 la = *(const short8*)qp, lb = *(const short8*)(qp + 32);
        short8 s0, s1;
#pragma unroll
        for (int e = 0; e < 8; e++) {
            s0[e] = (short)f2bf(bf2f((unsigned short)la[e]) * GAMMA);
            s1[e] = (short)f2bf(bf2f((unsigned short)lb[e]) * GAMMA);
        }
        qf[0] = __builtin_bit_cast(bf16x8, s0);
        qf[1] = __builtin_bit_cast(bf16x8, s1);
    }

    // K pointers (sigma row permutation), offset to tile ts
    const int srow = 8 * (n >> 2) + (n & 3);
    const unsigned short* kb0 = qk + (size_t)(b * SL + ts * 64) * LDQ + 1024 + h * DH + g * 8;
    const unsigned short* kp[4];
    kp[0] = kb0 + (size_t)(srow +  0) * LDQ;
    kp[1] = kb0 + (size_t)(srow +  4) * LDQ;
    kp[2] = kb0 + (size_t)(srow + 32) * LDQ;
    kp[3] = kb0 + (size_t)(srow + 36) * LDQ;
    // V pointers
    const unsigned short* vbp = vT + (size_t)bh * DH * SL;
    const unsigned short* vp[4];
#pragma unroll
    for (int df = 0; df < 4; df++) vp[df] = vbp + (size_t)(df * 16 + n) * SL + ts * 64 + g * 8;

    bf16x8 ka[4], kc[4], va[4], vc[4];
    f32x4 of[4];
#pragma unroll
    for (int i = 0; i < 4; i++) of[i] = (f32x4)(0.0f);
    float m_i = -1e30f, l_i = 0.0f;

    if (ts < te) {
        PREFETCH_K();   // K(ts)
        PREFETCH_V();   // V(ts)
        for (int t = ts; t < te; ++t) {
            f32x4 p[4];
            QKT(p, qf);
            if (t + 1 < te) PREFETCH_K();          // K(t+1): hidden by softmax+PV
            if (t == nt - 1) DIAG_MASK(p, qs, t * 64);
            bf16x8 f0, f1;
            SOFTMAX_PACK(p, m_i, l_i, of, f0, f1);
            PV(of, f0, f1);
            if (t + 1 < te) PREFETCH_V();          // V(t+1): hidden by full next iter
        }
    }

    // ---- flash-decoding combine: khalf 1 publishes, khalf 0 merges+writes ----
    if (khalf == 1) {
#pragma unroll
        for (int df = 0; df < 4; df++)
#pragma unroll
            for (int r = 0; r < 4; r++) mrg[sgrp][lane][df * 4 + r] = of[df][r];
        mrg[sgrp][lane][16] = m_i;
        mrg[sgrp][lane][17] = l_i;
    }
    __syncthreads();
    if (khalf == 0) {
        const float mH = mrg[sgrp][lane][16];
        const float lH = mrg[sgrp][lane][17];
        const float mc = fmaxf(m_i, mH);
        const float aL = __builtin_amdgcn_exp2f(m_i - mc);
        const float aH = __builtin_amdgcn_exp2f(mH - mc);
        float lc = l_i * aL + lH * aH;
        lc += __shfl_xor(lc, 16);
        lc += __shfl_xor(lc, 32);
        const float inv = 1.0f / lc;
        unsigned short* op = o + (size_t)(b * SL + qs) * 1024 + h * DH + 4 * g;
#pragma unroll
        for (int df = 0; df < 4; df++) {
            ushort4v st;
#pragma unroll
            for (int r = 0; r < 4; r++) {
                const float v = of[df][r] * aL + mrg[sgrp][lane][df * 4 + r] * aH;
                st[r] = f2bf(v * inv);
            }
            *(ushort4v*)(op + df * 16) = st;
        }
    }
}

// ---------------------------------------------------------------------------
extern "C" void kernel_launch(void* const* d_in, const int* in_sizes, int n_in,
                              void* d_out, int out_size, void* d_ws, size_t ws_size,
                              hipStream_t stream) {
    (void)in_sizes; (void)n_in; (void)out_size; (void)ws_size;
    const float* x    = (const float*)d_in[0];
    const float* Wqkv = (const float*)d_in[1];
    const float* bqkv = (const float*)d_in[2];
    const float* Wout = (const float*)d_in[3];
    const float* bout = (const float*)d_in[4];
    float* out = (float*)d_out;

    const int BS = 2, SL = 2048, DM = 1024;
    const int M = BS * SL;   // 4096
    const int N1 = 3 * DM;   // 3072
    const int K = DM;        // 1024

    // ws layout: x_bf 8M | wqkv_bf 6M | wout_bf 2M | qk 16M | vT 8M | attn_o 8M = 48M
    char* ws = (char*)d_ws;
    unsigned short* x_bf    = (unsigned short*)(ws);
    unsigned short* wqkv_bf = (unsigned short*)(ws + (8u << 20));
    unsigned short* wout_bf = (unsigned short*)(ws + (14u << 20));
    unsigned short* qkbuf   = (unsigned short*)(ws + (16u << 20));
    unsigned short* vTbuf   = (unsigned short*)(ws + (32u << 20));
    unsigned short* attn_o  = (unsigned short*)(ws + (40u << 20));

    cvt_f32_bf16<<<2048, 256, 0, stream>>>(x, x_bf, M * K / 8);
    cvt_f32_bf16<<<1536, 256, 0, stream>>>(Wqkv, wqkv_bf, N1 * K / 8);
    cvt_f32_bf16<<<512, 256, 0, stream>>>(Wout, wout_bf, DM * DM / 8);

    gemm_bt<1><<<dim3(N1 / 128, M / 128), 256, 0, stream>>>(x_bf, wqkv_bf, bqkv, qkbuf, vTbuf, M, N1, K);

    attn_fwd<<<dim3(2048), 256, 0, stream>>>(qkbuf, vTbuf, attn_o);

    gemm_bt<0><<<dim3(DM / 128, M / 128), 256, 0, stream>>>(attn_o, wout_bf, bout, out, nullptr, M, DM, K);
}

// Round 7
// 118.708 us; speedup vs baseline: 1.7321x; 1.7321x over previous
//
#include <hip/hip_runtime.h>
#include <cstdint>

typedef __attribute__((ext_vector_type(8))) __bf16 bf16x8;
typedef __attribute__((ext_vector_type(4))) float f32x4;
typedef __attribute__((ext_vector_type(8))) short short8;
typedef __attribute__((ext_vector_type(4))) float float4v;
typedef __attribute__((ext_vector_type(4))) unsigned uint4v;
typedef __attribute__((ext_vector_type(4))) unsigned short ushort4v;

__device__ __forceinline__ unsigned short f2bf(float f) {
    unsigned u = __builtin_bit_cast(unsigned, f);
    u += 0x7fffu + ((u >> 16) & 1u);   // RNE
    return (unsigned short)(u >> 16);
}
__device__ __forceinline__ float bf2f(unsigned short s) {
    return __builtin_bit_cast(float, (unsigned)s << 16);
}
__device__ __forceinline__ f32x4 mfma_bf16(bf16x8 a, bf16x8 b, f32x4 c) {
    return __builtin_amdgcn_mfma_f32_16x16x32_bf16(a, b, c, 0, 0, 0);
}
// pack 2 f32 -> 2 bf16 in one u32 (lo = first arg)
__device__ __forceinline__ unsigned pkbf(float lo, float hi) {
    unsigned r;
    asm("v_cvt_pk_bf16_f32 %0, %1, %2" : "=v"(r) : "v"(lo), "v"(hi));
    return r;
}

#define GLD16(g, l)                                                                     \
    __builtin_amdgcn_global_load_lds((const __attribute__((address_space(1))) void*)(g), \
                                     (__attribute__((address_space(3))) void*)(l), 16, 0, 0)

// ---------------------------------------------------------------------------
// fp32 -> bf16 conversion, 8 elems/thread.
// ---------------------------------------------------------------------------
__global__ void __launch_bounds__(256) cvt_f32_bf16(const float* __restrict__ src,
                                                    unsigned short* __restrict__ dst, int n8) {
    const int stride = gridDim.x * blockDim.x;
    for (int i = blockIdx.x * blockDim.x + threadIdx.x; i < n8; i += stride) {
        const float4v* s = (const float4v*)(src + (size_t)i * 8);
        float4v v0 = s[0], v1 = s[1];
        short8 o;
        o[0] = (short)f2bf(v0[0]); o[1] = (short)f2bf(v0[1]);
        o[2] = (short)f2bf(v0[2]); o[3] = (short)f2bf(v0[3]);
        o[4] = (short)f2bf(v1[0]); o[5] = (short)f2bf(v1[1]);
        o[6] = (short)f2bf(v1[2]); o[7] = (short)f2bf(v1[3]);
        *(short8*)(dst + (size_t)i * 8) = o;
    }
}

// ---------------------------------------------------------------------------
// C[M,N] = A[M,K]*B[N,K]^T + bias[N].  128x128 tile, BK=32, 4 waves, m97 structure.
// MODE 0: f32 C (ldc=N).   MODE 1 (QKV): n0<2048 -> bf16 qk buffer (ldc=2048);
//   n0>=2048 -> V part written TRANSPOSED into vT[bh][d=64][token=2048] bf16.
// ---------------------------------------------------------------------------
template <int MODE>
__global__ void __launch_bounds__(256) gemm_bt(const unsigned short* __restrict__ A,
                                               const unsigned short* __restrict__ B,
                                               const float* __restrict__ bias,
                                               void* __restrict__ C,
                                               unsigned short* __restrict__ vT,
                                               int M, int N, int K) {
    __shared__ __attribute__((aligned(16))) unsigned short As[128 * 32];
    __shared__ __attribute__((aligned(16))) unsigned short Bs[128 * 32];
    const int tid = threadIdx.x;
    const int w = tid >> 6, lane = tid & 63;
    const int a = lane & 15, g = lane >> 4;
    const int m0 = blockIdx.y * 128, n0 = blockIdx.x * 128;
    const int wr = (w >> 1) * 64, wc = (w & 1) * 64;

    f32x4 acc[4][4];
#pragma unroll
    for (int i = 0; i < 4; i++)
#pragma unroll
        for (int j = 0; j < 4; j++) acc[i][j] = (f32x4)(0.0f);

    const int r0 = tid >> 2;
    const int c0 = (tid & 3) * 8;
    const unsigned short* gA0 = A + (size_t)(m0 + r0) * K + c0;
    const unsigned short* gA1 = A + (size_t)(m0 + 64 + r0) * K + c0;
    const unsigned short* gB0 = B + (size_t)(n0 + r0) * K + c0;
    const unsigned short* gB1 = B + (size_t)(n0 + 64 + r0) * K + c0;
    char* ldsA = (char*)As + w * 1024;
    char* ldsB = (char*)Bs + w * 1024;

    for (int k0 = 0; k0 < K; k0 += 32) {
        GLD16(gA0 + k0, ldsA);
        GLD16(gA1 + k0, ldsA + 4096);
        GLD16(gB0 + k0, ldsB);
        GLD16(gB1 + k0, ldsB + 4096);
        __syncthreads();

        bf16x8 af[4], bfr[4];
#pragma unroll
        for (int i = 0; i < 4; i++) {
            af[i]  = *(const bf16x8*)&As[(wr + i * 16 + a) * 32 + g * 8];
            bfr[i] = *(const bf16x8*)&Bs[(wc + i * 16 + a) * 32 + g * 8];
        }
#pragma unroll
        for (int i = 0; i < 4; i++)
#pragma unroll
            for (int j = 0; j < 4; j++) acc[i][j] = mfma_bf16(af[i], bfr[j], acc[i][j]);
        __syncthreads();
    }

#pragma unroll
    for (int j = 0; j < 4; j++) {
        const int col = n0 + wc + j * 16 + a;
        const float bv = bias[col];
        if (MODE == 0) {
            float* Cf = (float*)C;
#pragma unroll
            for (int i = 0; i < 4; i++)
#pragma unroll
                for (int jr = 0; jr < 4; jr++) {
                    const int row = m0 + wr + i * 16 + g * 4 + jr;
                    Cf[(size_t)row * N + col] = acc[i][j][jr] + bv;
                }
        } else if (n0 < 2048) {  // Q/K part -> bf16, ldc = 2048
            unsigned short* Cb = (unsigned short*)C;
#pragma unroll
            for (int i = 0; i < 4; i++)
#pragma unroll
                for (int jr = 0; jr < 4; jr++) {
                    const int row = m0 + wr + i * 16 + g * 4 + jr;
                    Cb[(size_t)row * 2048 + col] = f2bf(acc[i][j][jr] + bv);
                }
        } else {  // V part -> vT[(b*16+h)][d][token], 4-token packs
            const int vd = col - 2048;
            const int hh = vd >> 6, dd = vd & 63;
#pragma unroll
            for (int i = 0; i < 4; i++) {
                const int token0 = m0 + wr + i * 16 + g * 4;
                const int bb = token0 >> 11, kl = token0 & 2047;
                ushort4v st;
#pragma unroll
                for (int jr = 0; jr < 4; jr++) st[jr] = f2bf(acc[i][j][jr] + bv);
                *(ushort4v*)(vT + ((size_t)((bb << 4) + hh) * 64 + dd) * 2048 + kl) = st;
            }
        }
    }
}

// ===========================================================================
// Causal flash attention v6b: swapped QK^T + in-register softmax (validated),
// K/V staged via global_load_lds into XOR-swizzled double-buffered LDS
// (zero-VGPR staging -> no scratch spill), one barrier/iteration.
// qk: [B*S, 2048] bf16 (Q | K), vT: [32][64][2048] bf16.
// Block = 4 waves x 16 q-rows = 64-row q-tile, all sharing staged K/V.
// Grid = 1024 blocks; qt-table keeps per-CU iteration totals constant.
// Swizzle (both-sides, rule 21): 16B-unit u at row r lives at u ^ xr(r),
//   xr(r) = (r&3) | (((r>>3)&1)<<2);  applied on global SOURCE (LDS linear).
// ===========================================================================

#define QKT_LDS(p, kvb)                                                 \
    {                                                                   \
        _Pragma("unroll") for (int nf_ = 0; nf_ < 4; nf_++) {           \
            const int r_ = srow + ((nf_ & 2) << 4) + ((nf_ & 1) << 2);  \
            const bf16x8 ka_ = *(const bf16x8*)&(kvb)[r_ * 64 + offKA]; \
            const bf16x8 kc_ = *(const bf16x8*)&(kvb)[r_ * 64 + offKB]; \
            f32x4 acc_ = (f32x4)(0.0f);                                 \
            acc_ = mfma_bf16(ka_, qf[0], acc_);                         \
            acc_ = mfma_bf16(kc_, qf[1], acc_);                         \
            p[nf_] = acc_;                                              \
        }                                                               \
    }

#define DIAG_MASK(p, qs_, k0_)                                          \
    {                                                                   \
        _Pragma("unroll") for (int nf_ = 0; nf_ < 4; nf_++) {           \
            const int kb_ = (k0_) + ((nf_ & 2) << 4) + ((nf_ & 1) << 2) + 8 * g; \
            _Pragma("unroll") for (int e_ = 0; e_ < 4; e_++)            \
                if (kb_ + e_ > (qs_)) p[nf_][e_] = -1e30f;              \
        }                                                               \
    }

// p in log2 domain. Updates m_,l_,of_; produces packed bf16 B-fragments.
#define SOFTMAX_PACK(p, m_, l_, of_, pf0, pf1)                          \
    {                                                                   \
        float x0 = fmaxf(fmaxf(p[0][0], p[0][1]), fmaxf(p[0][2], p[0][3])); \
        float x1 = fmaxf(fmaxf(p[1][0], p[1][1]), fmaxf(p[1][2], p[1][3])); \
        float x2 = fmaxf(fmaxf(p[2][0], p[2][1]), fmaxf(p[2][2], p[2][3])); \
        float x3 = fmaxf(fmaxf(p[3][0], p[3][1]), fmaxf(p[3][2], p[3][3])); \
        float mx = fmaxf(fmaxf(x0, x1), fmaxf(x2, x3));                 \
        mx = fmaxf(mx, __shfl_xor(mx, 16));                             \
        mx = fmaxf(mx, __shfl_xor(mx, 32));                             \
        if (!__all(mx <= m_ + 8.0f)) {                                  \
            const float mn_ = fmaxf(m_, mx);                            \
            const float al_ = __builtin_amdgcn_exp2f(m_ - mn_);         \
            l_ *= al_;                                                  \
            _Pragma("unroll") for (int d_ = 0; d_ < 4; d_++) of_[d_] = of_[d_] * al_; \
            m_ = mn_;                                                   \
        }                                                               \
        float rs_ = 0.0f;                                               \
        _Pragma("unroll") for (int nf_ = 0; nf_ < 4; nf_++)             \
            _Pragma("unroll") for (int e_ = 0; e_ < 4; e_++) {          \
                p[nf_][e_] = __builtin_amdgcn_exp2f(p[nf_][e_] - m_);   \
                rs_ += p[nf_][e_];                                      \
            }                                                           \
        l_ += rs_;                                                      \
        uint4v u0_, u1_;                                                \
        u0_[0] = pkbf(p[0][0], p[0][1]); u0_[1] = pkbf(p[0][2], p[0][3]); \
        u0_[2] = pkbf(p[1][0], p[1][1]); u0_[3] = pkbf(p[1][2], p[1][3]); \
        u1_[0] = pkbf(p[2][0], p[2][1]); u1_[1] = pkbf(p[2][2], p[2][3]); \
        u1_[2] = pkbf(p[3][0], p[3][1]); u1_[3] = pkbf(p[3][2], p[3][3]); \
        pf0 = __builtin_bit_cast(bf16x8, u0_);                          \
        pf1 = __builtin_bit_cast(bf16x8, u1_);                          \
    }

#define PV_LDS(of_, pf0, pf1, vb)                                       \
    {                                                                   \
        _Pragma("unroll") for (int df_ = 0; df_ < 4; df_++) {           \
            const bf16x8 va_ = *(const bf16x8*)&(vb)[(df_ * 16 + n) * 64 + offVA]; \
            const bf16x8 vc_ = *(const bf16x8*)&(vb)[(df_ * 16 + n) * 64 + offVB]; \
            of_[df_] = mfma_bf16(va_, pf0, of_[df_]);                   \
            of_[df_] = mfma_bf16(vc_, pf1, of_[df_]);                   \
        }                                                               \
    }

// stage tile t_ into buffer bf_: K 8KB + V 8KB, 4 x GLD16 per thread.
// LDS dest is LINEAR (wave base + lane*16); source address carries the swizzle.
#define STAGE(bf_, t_)                                                  \
    {                                                                   \
        const size_t ko_ = (size_t)(t_) * 64 * LDQ;                     \
        const size_t vo_ = (size_t)(t_) * 64;                           \
        char* db_ = (char*)&KV[bf_][0] + w * 1024;                      \
        GLD16(sK0 + ko_, db_);                                          \
        GLD16(sK1 + ko_, db_ + 4096);                                   \
        GLD16(sV0 + vo_, db_ + 8192);                                   \
        GLD16(sV1 + vo_, db_ + 12288);                                  \
    }

__global__ void __launch_bounds__(256) attn_fwd(const unsigned short* __restrict__ qk,
                                                const unsigned short* __restrict__ vT,
                                                unsigned short* __restrict__ o) {
    constexpr int SL = 2048, DH = 64, LDQ = 2048;
    constexpr float GAMMA = 0.18033688011112042f;  // 0.125 * log2(e)
    const int bh = blockIdx.x & 31;                // bh&7 == blockIdx&7 -> XCD pin
    const int s = blockIdx.x >> 5;                 // 0..31
    // qt table: any {s0, s0+8, s0+16, s0+24} sums to 62 -> per-CU balance
    const int qt = (s < 8) ? 31 - s : (s < 16) ? s - 8 : (s < 24) ? 39 - s : s - 16;
    const int b = bh >> 4, h = bh & 15;
    const int tid = threadIdx.x;
    const int w = tid >> 6, lane = tid & 63;
    const int n = lane & 15, g = lane >> 4;

    __shared__ __attribute__((aligned(16))) unsigned short KV[2][8192];  // [K 4096 | V 4096]

    const int q0 = qt * 64;
    const int qs = q0 + w * 16 + n;
    const int nt = qt + 1;

    // ---- Q fragments (B-operand), prescaled into log2 domain ----
    bf16x8 qf[2];
    {
        const unsigned short* qp = qk + (size_t)(b * SL + qs) * LDQ + h * DH + g * 8;
        short8 la = *(const short8*)qp, lb = *(const short8*)(qp + 32);
        short8 s0, s1;
#pragma unroll
        for (int e = 0; e < 8; e++) {
            s0[e] = (short)f2bf(bf2f((unsigned short)la[e]) * GAMMA);
            s1[e] = (short)f2bf(bf2f((unsigned short)lb[e]) * GAMMA);
        }
        qf[0] = __builtin_bit_cast(bf16x8, s0);
        qf[1] = __builtin_bit_cast(bf16x8, s1);
    }

    // ---- staging sources (per-lane, pre-swizzled) ----
    const int r0s = tid >> 3, u0s = tid & 7;
    const int xrs = (r0s & 3) | (((r0s >> 3) & 1) << 2);
    const int cs = ((u0s ^ xrs) << 3);
    const unsigned short* sK0 = qk + (size_t)(b * SL + r0s) * LDQ + 1024 + h * DH + cs;
    const unsigned short* sK1 = sK0 + (size_t)32 * LDQ;   // rows+32: xr unchanged
    const unsigned short* sV0 = vT + (size_t)bh * DH * SL + (size_t)r0s * SL + cs;
    const unsigned short* sV1 = sV0 + (size_t)32 * SL;

    // ---- fragment read offsets (swizzled) ----
    const int srow = 8 * (n >> 2) + (n & 3);
    const int xrq = (n & 3) | (((n >> 2) & 1) << 2);   // xr of QKT rows (all nf)
    const int offKA = ((g ^ xrq) << 3);
    const int offKB = offKA ^ 32;
    const int xrv = (n & 3) | (((n >> 3) & 1) << 2);   // xr of PV rows (all df)
    const int offVA = ((g ^ xrv) << 3);
    const int offVB = offVA ^ 32;

    f32x4 of[4];
#pragma unroll
    for (int i = 0; i < 4; i++) of[i] = (f32x4)(0.0f);
    float m_i = -1e30f, l_i = 0.0f;

    STAGE(0, 0);
    __syncthreads();  // drains vmcnt before barrier

    for (int t = 0; t < nt; ++t) {
        const unsigned short* kvb = &KV[t & 1][0];
        if (t + 1 < nt) STAGE((t & 1) ^ 1, t + 1);  // loads fly during compute

        f32x4 p[4];
        QKT_LDS(p, kvb);
        if (t == nt - 1) DIAG_MASK(p, qs, t * 64);
        bf16x8 f0, f1;
        SOFTMAX_PACK(p, m_i, l_i, of, f0, f1);
        PV_LDS(of, f0, f1, (kvb + 4096));

        __syncthreads();  // readers done with buf t&1; staged buf complete
    }

    // ---- epilogue: lane holds O[d = df*16+4g+r][q = qs] ----
    float rl = l_i;
    rl += __shfl_xor(rl, 16);
    rl += __shfl_xor(rl, 32);
    const float inv = 1.0f / rl;
    unsigned short* op = o + (size_t)(b * SL + qs) * 1024 + h * DH + 4 * g;
#pragma unroll
    for (int df = 0; df < 4; df++) {
        ushort4v st;
#pragma unroll
        for (int r = 0; r < 4; r++) st[r] = f2bf(of[df][r] * inv);
        *(ushort4v*)(op + df * 16) = st;
    }
}

// ---------------------------------------------------------------------------
extern "C" void kernel_launch(void* const* d_in, const int* in_sizes, int n_in,
                              void* d_out, int out_size, void* d_ws, size_t ws_size,
                              hipStream_t stream) {
    (void)in_sizes; (void)n_in; (void)out_size; (void)ws_size;
    const float* x    = (const float*)d_in[0];
    const float* Wqkv = (const float*)d_in[1];
    const float* bqkv = (const float*)d_in[2];
    const float* Wout = (const float*)d_in[3];
    const float* bout = (const float*)d_in[4];
    float* out = (float*)d_out;

    const int BS = 2, SL = 2048, DM = 1024;
    const int M = BS * SL;   // 4096
    const int N1 = 3 * DM;   // 3072
    const int K = DM;        // 1024

    // ws layout: x_bf 8M | wqkv_bf 6M | wout_bf 2M | qk 16M | vT 8M | attn_o 8M = 48M
    char* ws = (char*)d_ws;
    unsigned short* x_bf    = (unsigned short*)(ws);
    unsigned short* wqkv_bf = (unsigned short*)(ws + (8u << 20));
    unsigned short* wout_bf = (unsigned short*)(ws + (14u << 20));
    unsigned short* qkbuf   = (unsigned short*)(ws + (16u << 20));
    unsigned short* vTbuf   = (unsigned short*)(ws + (32u << 20));
    unsigned short* attn_o  = (unsigned short*)(ws + (40u << 20));

    cvt_f32_bf16<<<2048, 256, 0, stream>>>(x, x_bf, M * K / 8);
    cvt_f32_bf16<<<1536, 256, 0, stream>>>(Wqkv, wqkv_bf, N1 * K / 8);
    cvt_f32_bf16<<<512, 256, 0, stream>>>(Wout, wout_bf, DM * DM / 8);

    gemm_bt<1><<<dim3(N1 / 128, M / 128), 256, 0, stream>>>(x_bf, wqkv_bf, bqkv, qkbuf, vTbuf, M, N1, K);

    attn_fwd<<<dim3(1024), 256, 0, stream>>>(qkbuf, vTbuf, attn_o);

    gemm_bt<0><<<dim3(DM / 128, M / 128), 256, 0, stream>>>(attn_o, wout_bf, bout, out, nullptr, M, DM, K);
}

// Round 8
// 110.337 us; speedup vs baseline: 1.8635x; 1.0759x over previous
//
#include <hip/hip_runtime.h>
#include <cstdint>

typedef __attribute__((ext_vector_type(8))) __bf16 bf16x8;
typedef __attribute__((ext_vector_type(4))) float f32x4;
typedef __attribute__((ext_vector_type(8))) short short8;
typedef __attribute__((ext_vector_type(4))) float float4v;
typedef __attribute__((ext_vector_type(4))) unsigned uint4v;
typedef __attribute__((ext_vector_type(4))) unsigned short ushort4v;

__device__ __forceinline__ unsigned short f2bf(float f) {
    unsigned u = __builtin_bit_cast(unsigned, f);
    u += 0x7fffu + ((u >> 16) & 1u);   // RNE
    return (unsigned short)(u >> 16);
}
__device__ __forceinline__ float bf2f(unsigned short s) {
    return __builtin_bit_cast(float, (unsigned)s << 16);
}
__device__ __forceinline__ f32x4 mfma_bf16(bf16x8 a, bf16x8 b, f32x4 c) {
    return __builtin_amdgcn_mfma_f32_16x16x32_bf16(a, b, c, 0, 0, 0);
}
// pack 2 f32 -> 2 bf16 in one u32 (lo = first arg)
__device__ __forceinline__ unsigned pkbf(float lo, float hi) {
    unsigned r;
    asm("v_cvt_pk_bf16_f32 %0, %1, %2" : "=v"(r) : "v"(lo), "v"(hi));
    return r;
}

#define GLD16(g, l)                                                                     \
    __builtin_amdgcn_global_load_lds((const __attribute__((address_space(1))) void*)(g), \
                                     (__attribute__((address_space(3))) void*)(l), 16, 0, 0)

// ---------------------------------------------------------------------------
// fp32 -> bf16 conversion, 8 elems/thread.
// ---------------------------------------------------------------------------
__global__ void __launch_bounds__(256) cvt_f32_bf16(const float* __restrict__ src,
                                                    unsigned short* __restrict__ dst, int n8) {
    const int stride = gridDim.x * blockDim.x;
    for (int i = blockIdx.x * blockDim.x + threadIdx.x; i < n8; i += stride) {
        const float4v* s = (const float4v*)(src + (size_t)i * 8);
        float4v v0 = s[0], v1 = s[1];
        short8 o;
        o[0] = (short)f2bf(v0[0]); o[1] = (short)f2bf(v0[1]);
        o[2] = (short)f2bf(v0[2]); o[3] = (short)f2bf(v0[3]);
        o[4] = (short)f2bf(v1[0]); o[5] = (short)f2bf(v1[1]);
        o[6] = (short)f2bf(v1[2]); o[7] = (short)f2bf(v1[3]);
        *(short8*)(dst + (size_t)i * 8) = o;
    }
}

// ---------------------------------------------------------------------------
// C[M,N] = A[M,K]*B[N,K]^T + bias[N].  128x128 tile, BK=32, 4 waves.
// v8: 2-PHASE double-buffered LDS (T3 minimum recipe): STAGE(t+1) issued
// before compute(t), ONE barrier per K-step (load latency hides under MFMA).
// MODE 0: f32 C (ldc=N).   MODE 1 (QKV): n0<2048 -> bf16 qk buffer (ldc=2048);
//   n0>=2048 -> V part written TRANSPOSED into vT[bh][d=64][token=2048] bf16.
// ---------------------------------------------------------------------------
template <int MODE>
__global__ void __launch_bounds__(256) gemm_bt(const unsigned short* __restrict__ A,
                                               const unsigned short* __restrict__ B,
                                               const float* __restrict__ bias,
                                               void* __restrict__ C,
                                               unsigned short* __restrict__ vT,
                                               int M, int N, int K) {
    __shared__ __attribute__((aligned(16))) unsigned short As[2][128 * 32];
    __shared__ __attribute__((aligned(16))) unsigned short Bs[2][128 * 32];
    const int tid = threadIdx.x;
    const int w = tid >> 6, lane = tid & 63;
    const int a = lane & 15, g = lane >> 4;
    const int m0 = blockIdx.y * 128, n0 = blockIdx.x * 128;
    const int wr = (w >> 1) * 64, wc = (w & 1) * 64;

    f32x4 acc[4][4];
#pragma unroll
    for (int i = 0; i < 4; i++)
#pragma unroll
        for (int j = 0; j < 4; j++) acc[i][j] = (f32x4)(0.0f);

    const int r0 = tid >> 2;
    const int c0 = (tid & 3) * 8;
    const unsigned short* gA0 = A + (size_t)(m0 + r0) * K + c0;
    const unsigned short* gA1 = A + (size_t)(m0 + 64 + r0) * K + c0;
    const unsigned short* gB0 = B + (size_t)(n0 + r0) * K + c0;
    const unsigned short* gB1 = B + (size_t)(n0 + 64 + r0) * K + c0;

#define GSTAGE(buf_, k0_)                                               \
    {                                                                   \
        char* la_ = (char*)&As[buf_][0] + w * 1024;                     \
        char* lb_ = (char*)&Bs[buf_][0] + w * 1024;                     \
        GLD16(gA0 + (k0_), la_);                                        \
        GLD16(gA1 + (k0_), la_ + 4096);                                 \
        GLD16(gB0 + (k0_), lb_);                                        \
        GLD16(gB1 + (k0_), lb_ + 4096);                                 \
    }

    GSTAGE(0, 0);
    __syncthreads();   // vmcnt(0) drain: tile 0 resident

    int cur = 0;
    for (int k0 = 0; k0 < K; k0 += 32) {
        if (k0 + 32 < K) GSTAGE(cur ^ 1, k0 + 32);  // in flight across compute

        bf16x8 af[4], bfr[4];
#pragma unroll
        for (int i = 0; i < 4; i++) {
            af[i]  = *(const bf16x8*)&As[cur][(wr + i * 16 + a) * 32 + g * 8];
            bfr[i] = *(const bf16x8*)&Bs[cur][(wc + i * 16 + a) * 32 + g * 8];
        }
#pragma unroll
        for (int i = 0; i < 4; i++)
#pragma unroll
            for (int j = 0; j < 4; j++) acc[i][j] = mfma_bf16(af[i], bfr[j], acc[i][j]);

        __syncthreads();   // readers done with buf cur; prefetched buf complete
        cur ^= 1;
    }
#undef GSTAGE

#pragma unroll
    for (int j = 0; j < 4; j++) {
        const int col = n0 + wc + j * 16 + a;
        const float bv = bias[col];
        if (MODE == 0) {
            float* Cf = (float*)C;
#pragma unroll
            for (int i = 0; i < 4; i++)
#pragma unroll
                for (int jr = 0; jr < 4; jr++) {
                    const int row = m0 + wr + i * 16 + g * 4 + jr;
                    Cf[(size_t)row * N + col] = acc[i][j][jr] + bv;
                }
        } else if (n0 < 2048) {  // Q/K part -> bf16, ldc = 2048
            unsigned short* Cb = (unsigned short*)C;
#pragma unroll
            for (int i = 0; i < 4; i++)
#pragma unroll
                for (int jr = 0; jr < 4; jr++) {
                    const int row = m0 + wr + i * 16 + g * 4 + jr;
                    Cb[(size_t)row * 2048 + col] = f2bf(acc[i][j][jr] + bv);
                }
        } else {  // V part -> vT[(b*16+h)][d][token], 4-token packs
            const int vd = col - 2048;
            const int hh = vd >> 6, dd = vd & 63;
#pragma unroll
            for (int i = 0; i < 4; i++) {
                const int token0 = m0 + wr + i * 16 + g * 4;
                const int bb = token0 >> 11, kl = token0 & 2047;
                ushort4v st;
#pragma unroll
                for (int jr = 0; jr < 4; jr++) st[jr] = f2bf(acc[i][j][jr] + bv);
                *(ushort4v*)(vT + ((size_t)((bb << 4) + hh) * 64 + dd) * 2048 + kl) = st;
            }
        }
    }
}

// ===========================================================================
// Causal flash attention v6b (unchanged from Round 7): swapped QK^T +
// in-register softmax, K/V staged via global_load_lds into XOR-swizzled
// double-buffered LDS, one barrier/iteration.
// ===========================================================================

#define QKT_LDS(p, kvb)                                                 \
    {                                                                   \
        _Pragma("unroll") for (int nf_ = 0; nf_ < 4; nf_++) {           \
            const int r_ = srow + ((nf_ & 2) << 4) + ((nf_ & 1) << 2);  \
            const bf16x8 ka_ = *(const bf16x8*)&(kvb)[r_ * 64 + offKA]; \
            const bf16x8 kc_ = *(const bf16x8*)&(kvb)[r_ * 64 + offKB]; \
            f32x4 acc_ = (f32x4)(0.0f);                                 \
            acc_ = mfma_bf16(ka_, qf[0], acc_);                         \
            acc_ = mfma_bf16(kc_, qf[1], acc_);                         \
            p[nf_] = acc_;                                              \
        }                                                               \
    }

#define DIAG_MASK(p, qs_, k0_)                                          \
    {                                                                   \
        _Pragma("unroll") for (int nf_ = 0; nf_ < 4; nf_++) {           \
            const int kb_ = (k0_) + ((nf_ & 2) << 4) + ((nf_ & 1) << 2) + 8 * g; \
            _Pragma("unroll") for (int e_ = 0; e_ < 4; e_++)            \
                if (kb_ + e_ > (qs_)) p[nf_][e_] = -1e30f;              \
        }                                                               \
    }

// p in log2 domain. Updates m_,l_,of_; produces packed bf16 B-fragments.
#define SOFTMAX_PACK(p, m_, l_, of_, pf0, pf1)                          \
    {                                                                   \
        float x0 = fmaxf(fmaxf(p[0][0], p[0][1]), fmaxf(p[0][2], p[0][3])); \
        float x1 = fmaxf(fmaxf(p[1][0], p[1][1]), fmaxf(p[1][2], p[1][3])); \
        float x2 = fmaxf(fmaxf(p[2][0], p[2][1]), fmaxf(p[2][2], p[2][3])); \
        float x3 = fmaxf(fmaxf(p[3][0], p[3][1]), fmaxf(p[3][2], p[3][3])); \
        float mx = fmaxf(fmaxf(x0, x1), fmaxf(x2, x3));                 \
        mx = fmaxf(mx, __shfl_xor(mx, 16));                             \
        mx = fmaxf(mx, __shfl_xor(mx, 32));                             \
        if (!__all(mx <= m_ + 8.0f)) {                                  \
            const float mn_ = fmaxf(m_, mx);                            \
            const float al_ = __builtin_amdgcn_exp2f(m_ - mn_);         \
            l_ *= al_;                                                  \
            _Pragma("unroll") for (int d_ = 0; d_ < 4; d_++) of_[d_] = of_[d_] * al_; \
            m_ = mn_;                                                   \
        }                                                               \
        float rs_ = 0.0f;                                               \
        _Pragma("unroll") for (int nf_ = 0; nf_ < 4; nf_++)             \
            _Pragma("unroll") for (int e_ = 0; e_ < 4; e_++) {          \
                p[nf_][e_] = __builtin_amdgcn_exp2f(p[nf_][e_] - m_);   \
                rs_ += p[nf_][e_];                                      \
            }                                                           \
        l_ += rs_;                                                      \
        uint4v u0_, u1_;                                                \
        u0_[0] = pkbf(p[0][0], p[0][1]); u0_[1] = pkbf(p[0][2], p[0][3]); \
        u0_[2] = pkbf(p[1][0], p[1][1]); u0_[3] = pkbf(p[1][2], p[1][3]); \
        u1_[0] = pkbf(p[2][0], p[2][1]); u1_[1] = pkbf(p[2][2], p[2][3]); \
        u1_[2] = pkbf(p[3][0], p[3][1]); u1_[3] = pkbf(p[3][2], p[3][3]); \
        pf0 = __builtin_bit_cast(bf16x8, u0_);                          \
        pf1 = __builtin_bit_cast(bf16x8, u1_);                          \
    }

#define PV_LDS(of_, pf0, pf1, vb)                                       \
    {                                                                   \
        _Pragma("unroll") for (int df_ = 0; df_ < 4; df_++) {           \
            const bf16x8 va_ = *(const bf16x8*)&(vb)[(df_ * 16 + n) * 64 + offVA]; \
            const bf16x8 vc_ = *(const bf16x8*)&(vb)[(df_ * 16 + n) * 64 + offVB]; \
            of_[df_] = mfma_bf16(va_, pf0, of_[df_]);                   \
            of_[df_] = mfma_bf16(vc_, pf1, of_[df_]);                   \
        }                                                               \
    }

// stage tile t_ into buffer bf_: K 8KB + V 8KB, 4 x GLD16 per thread.
// LDS dest is LINEAR (wave base + lane*16); source address carries the swizzle.
#define STAGE(bf_, t_)                                                  \
    {                                                                   \
        const size_t ko_ = (size_t)(t_) * 64 * LDQ;                     \
        const size_t vo_ = (size_t)(t_) * 64;                           \
        char* db_ = (char*)&KV[bf_][0] + w * 1024;                      \
        GLD16(sK0 + ko_, db_);                                          \
        GLD16(sK1 + ko_, db_ + 4096);                                   \
        GLD16(sV0 + vo_, db_ + 8192);                                   \
        GLD16(sV1 + vo_, db_ + 12288);                                  \
    }

__global__ void __launch_bounds__(256) attn_fwd(const unsigned short* __restrict__ qk,
                                                const unsigned short* __restrict__ vT,
                                                unsigned short* __restrict__ o) {
    constexpr int SL = 2048, DH = 64, LDQ = 2048;
    constexpr float GAMMA = 0.18033688011112042f;  // 0.125 * log2(e)
    const int bh = blockIdx.x & 31;                // bh&7 == blockIdx&7 -> XCD pin
    const int s = blockIdx.x >> 5;                 // 0..31
    // qt table: any {s0, s0+8, s0+16, s0+24} sums to 62 -> per-CU balance
    const int qt = (s < 8) ? 31 - s : (s < 16) ? s - 8 : (s < 24) ? 39 - s : s - 16;
    const int b = bh >> 4, h = bh & 15;
    const int tid = threadIdx.x;
    const int w = tid >> 6, lane = tid & 63;
    const int n = lane & 15, g = lane >> 4;

    __shared__ __attribute__((aligned(16))) unsigned short KV[2][8192];  // [K 4096 | V 4096]

    const int q0 = qt * 64;
    const int qs = q0 + w * 16 + n;
    const int nt = qt + 1;

    // ---- Q fragments (B-operand), prescaled into log2 domain ----
    bf16x8 qf[2];
    {
        const unsigned short* qp = qk + (size_t)(b * SL + qs) * LDQ + h * DH + g * 8;
        short8 la = *(const short8*)qp, lb = *(const short8*)(qp + 32);
        short8 s0, s1;
#pragma unroll
        for (int e = 0; e < 8; e++) {
            s0[e] = (short)f2bf(bf2f((unsigned short)la[e]) * GAMMA);
            s1[e] = (short)f2bf(bf2f((unsigned short)lb[e]) * GAMMA);
        }
        qf[0] = __builtin_bit_cast(bf16x8, s0);
        qf[1] = __builtin_bit_cast(bf16x8, s1);
    }

    // ---- staging sources (per-lane, pre-swizzled) ----
    const int r0s = tid >> 3, u0s = tid & 7;
    const int xrs = (r0s & 3) | (((r0s >> 3) & 1) << 2);
    const int cs = ((u0s ^ xrs) << 3);
    const unsigned short* sK0 = qk + (size_t)(b * SL + r0s) * LDQ + 1024 + h * DH + cs;
    const unsigned short* sK1 = sK0 + (size_t)32 * LDQ;   // rows+32: xr unchanged
    const unsigned short* sV0 = vT + (size_t)bh * DH * SL + (size_t)r0s * SL + cs;
    const unsigned short* sV1 = sV0 + (size_t)32 * SL;

    // ---- fragment read offsets (swizzled) ----
    const int srow = 8 * (n >> 2) + (n & 3);
    const int xrq = (n & 3) | (((n >> 2) & 1) << 2);   // xr of QKT rows (all nf)
    const int offKA = ((g ^ xrq) << 3);
    const int offKB = offKA ^ 32;
    const int xrv = (n & 3) | (((n >> 3) & 1) << 2);   // xr of PV rows (all df)
    const int offVA = ((g ^ xrv) << 3);
    const int offVB = offVA ^ 32;

    f32x4 of[4];
#pragma unroll
    for (int i = 0; i < 4; i++) of[i] = (f32x4)(0.0f);
    float m_i = -1e30f, l_i = 0.0f;

    STAGE(0, 0);
    __syncthreads();  // drains vmcnt before barrier

    for (int t = 0; t < nt; ++t) {
        const unsigned short* kvb = &KV[t & 1][0];
        if (t + 1 < nt) STAGE((t & 1) ^ 1, t + 1);  // loads fly during compute

        f32x4 p[4];
        QKT_LDS(p, kvb);
        if (t == nt - 1) DIAG_MASK(p, qs, t * 64);
        bf16x8 f0, f1;
        SOFTMAX_PACK(p, m_i, l_i, of, f0, f1);
        PV_LDS(of, f0, f1, (kvb + 4096));

        __syncthreads();  // readers done with buf t&1; staged buf complete
    }

    // ---- epilogue: lane holds O[d = df*16+4g+r][q = qs] ----
    float rl = l_i;
    rl += __shfl_xor(rl, 16);
    rl += __shfl_xor(rl, 32);
    const float inv = 1.0f / rl;
    unsigned short* op = o + (size_t)(b * SL + qs) * 1024 + h * DH + 4 * g;
#pragma unroll
    for (int df = 0; df < 4; df++) {
        ushort4v st;
#pragma unroll
        for (int r = 0; r < 4; r++) st[r] = f2bf(of[df][r] * inv);
        *(ushort4v*)(op + df * 16) = st;
    }
}

// ---------------------------------------------------------------------------
extern "C" void kernel_launch(void* const* d_in, const int* in_sizes, int n_in,
                              void* d_out, int out_size, void* d_ws, size_t ws_size,
                              hipStream_t stream) {
    (void)in_sizes; (void)n_in; (void)out_size; (void)ws_size;
    const float* x    = (const float*)d_in[0];
    const float* Wqkv = (const float*)d_in[1];
    const float* bqkv = (const float*)d_in[2];
    const float* Wout = (const float*)d_in[3];
    const float* bout = (const float*)d_in[4];
    float* out = (float*)d_out;

    const int BS = 2, SL = 2048, DM = 1024;
    const int M = BS * SL;   // 4096
    const int N1 = 3 * DM;   // 3072
    const int K = DM;        // 1024

    // ws layout: x_bf 8M | wqkv_bf 6M | wout_bf 2M | qk 16M | vT 8M | attn_o 8M = 48M
    char* ws = (char*)d_ws;
    unsigned short* x_bf    = (unsigned short*)(ws);
    unsigned short* wqkv_bf = (unsigned short*)(ws + (8u << 20));
    unsigned short* wout_bf = (unsigned short*)(ws + (14u << 20));
    unsigned short* qkbuf   = (unsigned short*)(ws + (16u << 20));
    unsigned short* vTbuf   = (unsigned short*)(ws + (32u << 20));
    unsigned short* attn_o  = (unsigned short*)(ws + (40u << 20));

    cvt_f32_bf16<<<2048, 256, 0, stream>>>(x, x_bf, M * K / 8);
    cvt_f32_bf16<<<1536, 256, 0, stream>>>(Wqkv, wqkv_bf, N1 * K / 8);
    cvt_f32_bf16<<<512, 256, 0, stream>>>(Wout, wout_bf, DM * DM / 8);

    gemm_bt<1><<<dim3(N1 / 128, M / 128), 256, 0, stream>>>(x_bf, wqkv_bf, bqkv, qkbuf, vTbuf, M, N1, K);

    attn_fwd<<<dim3(1024), 256, 0, stream>>>(qkbuf, vTbuf, attn_o);

    gemm_bt<0><<<dim3(DM / 128, M / 128), 256, 0, stream>>>(attn_o, wout_bf, bout, out, nullptr, M, DM, K);
}